// Round 14
// baseline (603.014 us; speedup 1.0000x reference)
//
#include <hip/hip_runtime.h>

#define C    512
#define NDIM 1024
#define BDIM 8
#define TDIM 4
#define HDIM 8
#define CN   (C*NDIM)        // 524288
#define BCN  (BDIM*CN)       // 4194304

typedef unsigned short u16;
typedef unsigned int   u32;
typedef unsigned long long u64;
typedef __attribute__((ext_vector_type(8))) short bf8v;      // 8 bf16 (4 VGPR)
typedef __attribute__((ext_vector_type(8))) _Float16 h8v;    // 8 fp16 (4 VGPR)
typedef __attribute__((ext_vector_type(4))) float f4v;       // 4 fp32 acc
typedef __attribute__((ext_vector_type(2))) float f2v;       // packed fp32 pair

// round-to-nearest-even f32 -> bf16 (finite inputs only)
__device__ __forceinline__ u16 f2bf(float f) {
    u32 u = __float_as_uint(f);
    u32 r = u + 0x7FFFu + ((u >> 16) & 1u);
    return (u16)(r >> 16);
}
__device__ __forceinline__ float bf2f(u16 h) { return __uint_as_float((u32)h << 16); }

#if defined(__has_builtin)
#if __has_builtin(__builtin_amdgcn_global_load_lds)
#define HAS_GLL 1
#endif
#if __has_builtin(__builtin_elementwise_fma)
#define HAS_EFMA 1
#endif
#endif
#ifdef HAS_GLL
#define GLD(gp, lp) __builtin_amdgcn_global_load_lds( \
    (const __attribute__((address_space(1))) u32*)(gp), \
    (__attribute__((address_space(3))) u32*)(lp), 16, 0, 0)
#else
#define GLD(gp, lp) (*(uint4*)(lp) = *(const uint4*)(const void*)(gp))
#endif

__device__ __forceinline__ f2v pkfma(f2v a, f2v b, f2v c) {
#ifdef HAS_EFMA
    return __builtin_elementwise_fma(a, b, c);
#else
    f2v r; r.x = fmaf(a.x, b.x, c.x); r.y = fmaf(a.y, b.y, c.y); return r;
#endif
}

// ---------------------------------------------------------------------------
// Merged in_proj fp32 GEMM v4: A in LDS (double-buffered, 1 barrier/k0),
// B read DIRECT from global/L1 (256 B contiguous per wave-load, 4-way lane
// broadcast) — halves LDS traffic; VALU-fmac (82 µs/CU floor) becomes the
// bound. Same B values, same strictly k-ascending per-output fma chain as
// R6..R13 -> bit-identical Y.  grid (8 nblk, 4 mblk, 24 = br*8+b)
// ---------------------------------------------------------------------------
__global__ __launch_bounds__(256) void gemm_in3_k(
    const float* __restrict__ W, const float* __restrict__ bias,
    const float* __restrict__ Xq, const float* __restrict__ Xk,
    const float* __restrict__ Xv, float* __restrict__ Y3)
{
    __shared__ float As[2][16][132];   // [buf][k][m], pad 132
    const int tid = threadIdx.x;
    const int bz = blockIdx.z;               // br*8 + b
    const int br = bz >> 3, b = bz & 7;
    const int m0 = blockIdx.y * 128;
    const int n0 = blockIdx.x * 128;
    const float* Xb = (br == 0 ? Xq : (br == 1 ? Xk : Xv)) + (size_t)b * CN;
    const int rowOff = br * 512;

    const int ra = tid >> 2, ka = (tid & 3) * 4;
    const int tx = tid & 15, ty = tid >> 4;

    const float* pA0 = &W[(size_t)(rowOff + m0 + ra) * 512 + ka];
    const float* pA1 = &W[(size_t)(rowOff + m0 + 64 + ra) * 512 + ka];
    const float* pBlo = &Xb[n0 + tx * 4];        // + (k0+k)*NDIM
    const float* pBhi = &Xb[n0 + 64 + tx * 4];

    f2v acc[2][2][4][2];   // [mq][nq][i][jp]
    #pragma unroll
    for (int mq = 0; mq < 2; mq++)
        #pragma unroll
        for (int nq = 0; nq < 2; nq++)
            #pragma unroll
            for (int i = 0; i < 4; i++)
                #pragma unroll
                for (int jp = 0; jp < 2; jp++) acc[mq][nq][i][jp] = (f2v){0.f, 0.f};

    // prologue: stage A tile 0 into buffer 0
    {
        float4 a0 = *(const float4*)pA0;
        float4 a1 = *(const float4*)pA1;
        As[0][ka + 0][ra] = a0.x; As[0][ka + 1][ra] = a0.y;
        As[0][ka + 2][ra] = a0.z; As[0][ka + 3][ra] = a0.w;
        As[0][ka + 0][64 + ra] = a1.x; As[0][ka + 1][64 + ra] = a1.y;
        As[0][ka + 2][64 + ra] = a1.z; As[0][ka + 3][64 + ra] = a1.w;
    }
    __syncthreads();

    for (int k0 = 0; k0 < 512; k0 += 16) {
        const int p = (k0 >> 4) & 1;
        const bool more = (k0 < 496);
        float4 na0, na1;
        if (more) {
            na0 = *(const float4*)(pA0 + k0 + 16);
            na1 = *(const float4*)(pA1 + k0 + 16);
        }
        #pragma unroll
        for (int k = 0; k < 16; k++) {
            float av[2][4];
            f2v bv[2][2];
            *(float4*)av[0] = *(const float4*)&As[p][k][ty * 4];
            *(float4*)av[1] = *(const float4*)&As[p][k][64 + ty * 4];
            float4 bq0 = *(const float4*)(pBlo + (size_t)(k0 + k) * NDIM);
            float4 bq1 = *(const float4*)(pBhi + (size_t)(k0 + k) * NDIM);
            bv[0][0] = (f2v){bq0.x, bq0.y}; bv[0][1] = (f2v){bq0.z, bq0.w};
            bv[1][0] = (f2v){bq1.x, bq1.y}; bv[1][1] = (f2v){bq1.z, bq1.w};
            #pragma unroll
            for (int mq = 0; mq < 2; mq++)
                #pragma unroll
                for (int i = 0; i < 4; i++) {
                    const f2v a2 = (f2v){av[mq][i], av[mq][i]};
                    #pragma unroll
                    for (int nq = 0; nq < 2; nq++)
                        #pragma unroll
                        for (int jp = 0; jp < 2; jp++)
                            acc[mq][nq][i][jp] = pkfma(a2, bv[nq][jp], acc[mq][nq][i][jp]);
                }
        }
        if (more) {
            // write next A tile into the idle buffer; reads of buffer p are
            // done above; prior-iteration reads of p^1 were fenced by the
            // barrier below in the previous iteration.
            As[p ^ 1][ka + 0][ra] = na0.x; As[p ^ 1][ka + 1][ra] = na0.y;
            As[p ^ 1][ka + 2][ra] = na0.z; As[p ^ 1][ka + 3][ra] = na0.w;
            As[p ^ 1][ka + 0][64 + ra] = na1.x; As[p ^ 1][ka + 1][64 + ra] = na1.y;
            As[p ^ 1][ka + 2][64 + ra] = na1.z; As[p ^ 1][ka + 3][64 + ra] = na1.w;
        }
        __syncthreads();
    }
    #pragma unroll
    for (int mq = 0; mq < 2; mq++)
        #pragma unroll
        for (int i = 0; i < 4; i++) {
            const int mrow = mq * 64 + ty * 4 + i;
            float bsv = bias[rowOff + m0 + mrow];
            float* yr = Y3 + (size_t)bz * CN + (size_t)(m0 + mrow) * NDIM + n0;
            #pragma unroll
            for (int nq = 0; nq < 2; nq++) {
                float4 o4 = make_float4(acc[mq][nq][i][0].x + bsv, acc[mq][nq][i][0].y + bsv,
                                        acc[mq][nq][i][1].x + bsv, acc[mq][nq][i][1].y + bsv);
                *(float4*)&yr[nq * 64 + tx * 4] = o4;
            }
        }
}

// ---------------------------------------------------------------------------
// Fused two-pass per-channel stats (R7/R8-proven, bit-exact vs R6 pair)
// ---------------------------------------------------------------------------
__global__ __launch_bounds__(256) void chan_stats2_k(
    const float* __restrict__ X3, float* __restrict__ mean3,
    float* __restrict__ rstd3, int outer)
{
    __shared__ float red[256];
    __shared__ float m_sh;
    const int gb = blockIdx.x;
    const int o = gb & (C - 1);
    const float* X = X3 + (size_t)(gb >> 9) * BCN;
    const int tid = threadIdx.x;
    const int total = outer * NDIM;
    float s = 0.f;
    for (int i = tid; i < total; i += 256) {
        int ou = i >> 10, n = i & 1023;
        s += X[(size_t)(ou * C + o) * NDIM + n];
    }
    red[tid] = s; __syncthreads();
    for (int off = 128; off > 0; off >>= 1) {
        if (tid < off) red[tid] += red[tid + off];
        __syncthreads();
    }
    if (tid == 0) { float m = red[0] / (float)total; mean3[gb] = m; m_sh = m; }
    __syncthreads();
    const float m = m_sh;
    float s2 = 0.f;
    for (int i = tid; i < total; i += 256) {
        int ou = i >> 10, n = i & 1023;
        float d = X[(size_t)(ou * C + o) * NDIM + n] - m;
        s2 += d * d;
    }
    red[tid] = s2; __syncthreads();
    for (int off = 128; off > 0; off >>= 1) {
        if (tid < off) red[tid] += red[tid + off];
        __syncthreads();
    }
    if (tid == 0) rstd3[gb] = 1.f / sqrtf(red[0] / (float)total + 1e-5f);
}

// ---------------------------------------------------------------------------
// One dispatch: Q BN+LIF+qpack, K/V BN+LIF+bitpack, PW split (R7/R8-proven)
// ---------------------------------------------------------------------------
__global__ __launch_bounds__(256) void spikes_k(
    const float* __restrict__ Y3, const float* __restrict__ mean3,
    const float* __restrict__ rstd3,
    const float* __restrict__ qg, const float* __restrict__ qb,
    const float* __restrict__ kg, const float* __restrict__ kbt,
    const float* __restrict__ vg, const float* __restrict__ vbt,
    const float* __restrict__ PW,
    u64* __restrict__ qm, u64* __restrict__ kbits, u64* __restrict__ vbits,
    u16* __restrict__ Ps)
{
    __shared__ unsigned char tile[64][68];
    const int tid = threadIdx.x;
    const int bid = blockIdx.x;
    if (bid < 1024) {
        const int b = bid >> 7, h = (bid >> 4) & 7, nt = bid & 15;
        const int c_l = tid >> 2, sg = (tid & 3) * 16;
        const int o = h * 64 + c_l;
        const float m = mean3[o], rs = rstd3[o], g = qg[o], bt = qb[o];
        const float* Yr = Y3 + ((size_t)b * C + o) * NDIM + nt * 64 + sg;
        #pragma unroll
        for (int j = 0; j < 4; j++) {
            float4 y4 = *(const float4*)&Yr[j * 4];
            float ys[4] = {y4.x, y4.y, y4.z, y4.w};
            #pragma unroll
            for (int e = 0; e < 4; e++) {
                float x = g * (ys[e] - m);
                x = x * rs + bt;
                float v = 0.f; unsigned bits = 0;
                #pragma unroll
                for (int t = 0; t < 4; t++) {
                    v += (x - v) * 0.5f;
                    if (v - 1.0f >= 0.f) { bits |= (1u << t); v = 0.f; }
                }
                tile[c_l][sg + j * 4 + e] = (unsigned char)bits;
            }
        }
        __syncthreads();
        const int lane = tid & 63, wv = tid >> 6;
        #pragma unroll
        for (int i = 0; i < 16; i++) {
            const int nl = wv * 16 + i;
            unsigned s = tile[lane][nl];
            #pragma unroll
            for (int t = 0; t < 4; t++) {
                u64 mk = __ballot((s >> t) & 1);
                if (lane == t)
                    qm[(size_t)((t * BDIM + b) * HDIM + h) * NDIM + nt * 64 + nl] = mk;
            }
        }
    } else if (bid < 3072) {
        const int r = bid - 1024;
        const int br = r >> 10;                       // 0:K 1:V
        const int rr = r & 1023;
        const int b = rr >> 7, ct = (rr >> 4) & 7, nt = rr & 15;
        const float* Yb = Y3 + (size_t)(br + 1) * BCN + (size_t)b * CN;
        const float* mean = mean3 + (br + 1) * C;
        const float* rstd = rstd3 + (br + 1) * C;
        const float* gam = br == 0 ? kg : vg;
        const float* bet = br == 0 ? kbt : vbt;
        u64* bits = br == 0 ? kbits : vbits;
        const int lane = tid & 63, wv = tid >> 6;
        #pragma unroll
        for (int i = 0; i < 16; i++) {
            const int o = ct * 64 + wv * 16 + i;
            const float m = mean[o], rs = rstd[o], g = gam[o], bt = bet[o];
            float y = Yb[(size_t)o * NDIM + nt * 64 + lane];
            float x = g * (y - m);
            x = x * rs + bt;
            float v = 0.f; unsigned sb = 0;
            #pragma unroll
            for (int t = 0; t < 4; t++) {
                v += (x - v) * 0.5f;
                if (v - 1.0f >= 0.f) { sb |= (1u << t); v = 0.f; }
            }
            #pragma unroll
            for (int t = 0; t < 4; t++) {
                u64 mk = __ballot((sb >> t) & 1);
                if (lane == t)
                    bits[((size_t)(t * BDIM + b) * C + o) * 16 + nt] = mk;
            }
        }
    } else {
        const int idx = (bid - 3072) * 256 + tid;     // 262144 PW elements
        float x = PW[idx];
        u16 h1 = f2bf(x); float r1 = x - bf2f(h1);
        u16 h2 = f2bf(r1); float r2 = r1 - bf2f(h2);
        u16 h3 = f2bf(r2);
        Ps[idx] = h1; Ps[idx + 262144] = h2; Ps[idx + 2 * 262144] = h3;
    }
}

// ---------------------------------------------------------------------------
// ktvT[t,b,h,e,dd] = popcount(K & V), transposed, fp16-exact (R10-proven)
// ---------------------------------------------------------------------------
__global__ __launch_bounds__(256) void ktvT_k(
    const u64* __restrict__ kb, const u64* __restrict__ vb,
    _Float16* __restrict__ ktvT)
{
    __shared__ u64 kst[64][17];
    __shared__ u64 vst[64][17];
    const int tid = threadIdx.x;
    const int g = blockIdx.x;
    const int h = g & 7, b = (g >> 3) & 7, t = g >> 6;
    const size_t base = ((size_t)(t * BDIM + b) * C + h * 64) * 16;
    {
        int r = tid >> 2, w0 = (tid & 3) * 4;
        #pragma unroll
        for (int j = 0; j < 4; j++) {
            kst[r][w0 + j] = kb[base + r * 16 + w0 + j];
            vst[r][w0 + j] = vb[base + r * 16 + w0 + j];
        }
    }
    __syncthreads();
    const int e = tid >> 2, dd0 = (tid & 3) * 16;
    u64 vr[16];
    #pragma unroll
    for (int w = 0; w < 16; w++) vr[w] = vst[e][w];
    #pragma unroll
    for (int i = 0; i < 16; i++) {
        int dd = dd0 + i;
        int s = 0;
        #pragma unroll
        for (int w = 0; w < 16; w++) s += __popcll(kst[dd][w] & vr[w]);
        ktvT[(size_t)(g * 64 + e) * 64 + dd] = (_Float16)s;
    }
}

// ---------------------------------------------------------------------------
// att via fp16 MFMA (exact) + attn LIF (vth=0.5)  (R10-proven)
// ---------------------------------------------------------------------------
__global__ __launch_bounds__(256) void att_mfma_k(
    const _Float16* __restrict__ ktvT, const u64* __restrict__ qm,
    unsigned char* __restrict__ spkT)
{
    const int tid = threadIdx.x;
    const int w = tid >> 6, lane = tid & 63;
    const int ln = lane & 15, q = lane >> 4;
    const int bh = blockIdx.x; const int h = bh & 7, b = bh >> 3;
    const int n0 = blockIdx.y * 64 + w * 16;

    float v[4][4];
    u32 bits[4][4];
    #pragma unroll
    for (int et = 0; et < 4; et++)
        #pragma unroll
        for (int r = 0; r < 4; r++) { v[et][r] = 0.f; bits[et][r] = 0u; }

    #pragma unroll
    for (int t = 0; t < 4; t++) {
        const size_t gq = (size_t)(t * BDIM + b) * HDIM + h;
        const u64 qw = qm[gq * NDIM + n0 + ln];
        union { u16 s[8]; h8v v8; } a0u, a1u;
        #pragma unroll
        for (int j = 0; j < 8; j++) {
            a0u.s[j] = (u16)(((qw >> (q * 8 + j)) & 1ull) ? 0x3C00u : 0u);
            a1u.s[j] = (u16)(((qw >> (32 + q * 8 + j)) & 1ull) ? 0x3C00u : 0u);
        }
        const _Float16* kbp = ktvT + gq * 4096;
        f4v acc[4];
        #pragma unroll
        for (int et = 0; et < 4; et++) acc[et] = (f4v){0.f, 0.f, 0.f, 0.f};
        #pragma unroll
        for (int et = 0; et < 4; et++) {
            h8v b0 = *(const h8v*)(kbp + (et * 16 + ln) * 64 + q * 8);
            h8v b1 = *(const h8v*)(kbp + (et * 16 + ln) * 64 + 32 + q * 8);
            acc[et] = __builtin_amdgcn_mfma_f32_16x16x32_f16(a0u.v8, b0, acc[et], 0, 0, 0);
            acc[et] = __builtin_amdgcn_mfma_f32_16x16x32_f16(a1u.v8, b1, acc[et], 0, 0, 0);
        }
        #pragma unroll
        for (int et = 0; et < 4; et++)
            #pragma unroll
            for (int r = 0; r < 4; r++) {
                float x = acc[et][r] * 0.125f;     // exact dyadic
                float vv = v[et][r];
                vv += (x - vv) * 0.5f;
                if (vv - 0.5f >= 0.f) { bits[et][r] |= (1u << t); vv = 0.f; }
                v[et][r] = vv;
            }
    }
    #pragma unroll
    for (int et = 0; et < 4; et++)
        #pragma unroll
        for (int r = 0; r < 4; r++)
            spkT[((size_t)b * 1024 + n0 + q * 4 + r) * 512 + h * 64 + et * 16 + ln] =
                (unsigned char)bits[et][r];
}

// ---------------------------------------------------------------------------
// proj MFMA GEMM over spikes (R3-PROVEN version — 81 µs plateau)
// ---------------------------------------------------------------------------
__global__ __launch_bounds__(256, 2) void gemm_proj_mfma(
    const u16* __restrict__ Ps, const unsigned char* __restrict__ spkT,
    float* __restrict__ Z)
{
    __shared__ __align__(16) u16 Ab[2][12288];   // 3 splits x 4096
    __shared__ __align__(16) u16 Bb[2][4096];
    const int tid = threadIdx.x;
    const int zb = blockIdx.z, t = zb >> 3, bb = zb & 7;
    const int m0 = blockIdx.y * 128, n0 = blockIdx.x * 128;

    u32 aoff[2][3];
    int lofs[2];
    #pragma unroll
    for (int r = 0; r < 2; r++) {
        const int cid = tid + (r << 8);
        const int mm = cid & 15, kg = (cid >> 4) & 3, mt = cid >> 6;
        lofs[r] = cid * 8;
        #pragma unroll
        for (int s = 0; s < 3; s++)
            aoff[r][s] = (u32)s * 262144u + (u32)(m0 + mt * 16 + mm) * 512u + kg * 8;
    }
    auto stageA = [&](int ki2, int p2) {
        const u32 kk = (u32)ki2 << 5;
        #pragma unroll
        for (int r = 0; r < 2; r++)
            #pragma unroll
            for (int s = 0; s < 3; s++)
                GLD(Ps + aoff[r][s] + kk, &Ab[p2][s * 4096 + lofs[r]]);
    };
    const int nn = tid & 15, ntl = (tid >> 4) & 7, seg = tid >> 7;
    const u32 srcB = ((u32)bb * 1024u + (u32)(n0 + ntl * 16 + nn)) * 512u + seg * 16;
    const int ldsB0 = (ntl * 64 + seg * 32 + nn) * 8;
    auto convB = [&](uint4 braw, int p2) {
        u32 bs[4] = {braw.x, braw.y, braw.z, braw.w};
        u32 wreg[8];
        #pragma unroll
        for (int qq = 0; qq < 4; qq++) {
            u32 vv = bs[qq] >> t;
            wreg[qq * 2 + 0] = ((vv & 1u) ? 0x3F80u : 0u) | ((vv & 0x100u) ? 0x3F800000u : 0u);
            wreg[qq * 2 + 1] = (((vv >> 16) & 1u) ? 0x3F80u : 0u) | ((vv & 0x1000000u) ? 0x3F800000u : 0u);
        }
        *(uint4*)&Bb[p2][ldsB0]       = make_uint4(wreg[0], wreg[1], wreg[2], wreg[3]);
        *(uint4*)&Bb[p2][ldsB0 + 128] = make_uint4(wreg[4], wreg[5], wreg[6], wreg[7]);
    };

    const int lane = tid & 63, wv = tid >> 6;
    const int wm = wv >> 1, wn = wv & 1;
    const int q = lane >> 4, ln = lane & 15;
    int afo[4], bfo[4];
    #pragma unroll
    for (int i = 0; i < 4; i++) {
        afo[i] = ((wm * 4 + i) * 64 + q * 16 + ln) * 8;
        bfo[i] = ((wn * 4 + i) * 64 + q * 16 + ln) * 8;
    }

    f4v acc[4][4];
    #pragma unroll
    for (int i = 0; i < 4; i++)
        #pragma unroll
        for (int j = 0; j < 4; j++) acc[i][j] = (f4v){0.f, 0.f, 0.f, 0.f};

    stageA(0, 0);
    convB(*(const uint4*)&spkT[srcB], 0);
    uint4 braw;
    for (int ki = 0; ki < 16; ki++) {
        const int p = ki & 1;
        __syncthreads();
        if (ki < 15) {
            stageA(ki + 1, p ^ 1);
            braw = *(const uint4*)&spkT[srcB + ((u32)(ki + 1) << 5)];
        }
        bf8v bf[4];
        #pragma unroll
        for (int j = 0; j < 4; j++) bf[j] = *(const bf8v*)&Bb[p][bfo[j]];
        #pragma unroll
        for (int sa = 0; sa < 3; sa++) {
            bf8v af[4];
            #pragma unroll
            for (int i = 0; i < 4; i++) af[i] = *(const bf8v*)&Ab[p][sa * 4096 + afo[i]];
            #pragma unroll
            for (int i = 0; i < 4; i++)
                #pragma unroll
                for (int j = 0; j < 4; j++)
                    acc[i][j] = __builtin_amdgcn_mfma_f32_16x16x32_bf16(af[i], bf[j], acc[i][j], 0, 0, 0);
        }
        if (ki < 15) convB(braw, p ^ 1);
    }
    float* Zb = Z + (size_t)zb * CN;
    #pragma unroll
    for (int i = 0; i < 4; i++) {
        const int row = m0 + (wm * 4 + i) * 16 + q * 4;
        #pragma unroll
        for (int g = 0; g < 4; g++) {
            float* zr = Zb + (size_t)(row + g) * 1024 + n0 + ln;
            #pragma unroll
            for (int j = 0; j < 4; j++)
                zr[(wn * 4 + j) * 16] = acc[i][j][g];
        }
    }
}

// ---------------------------------------------------------------------------
// Final BN + LIF (vth=1, time-varying) in place over d_out.  (R3-proven)
// ---------------------------------------------------------------------------
__global__ __launch_bounds__(256) void final_bn_lif_k(
    float* __restrict__ Z, const float* __restrict__ mean,
    const float* __restrict__ rstd, const float* __restrict__ gamma,
    const float* __restrict__ beta)
{
    const int idx = blockIdx.x * 256 + threadIdx.x;
    const int o = (idx >> 10) & (C - 1);
    const float m = mean[o], rs = rstd[o], g = gamma[o], bt = beta[o];
    float v = 0.f;
    float outs[4];
    #pragma unroll
    for (int t = 0; t < 4; t++) {
        float z = Z[(size_t)t * BCN + idx];
        float x = g * (z - m);
        x = x * rs + bt;
        v += (x - v) * 0.5f;
        float s = (v - 1.0f >= 0.f) ? 1.f : 0.f;
        v *= (1.f - s);
        outs[t] = s;
    }
    #pragma unroll
    for (int t = 0; t < 4; t++) Z[(size_t)t * BCN + idx] = outs[t];
}

// ---------------------------------------------------------------------------
extern "C" void kernel_launch(void* const* d_in, const int* in_sizes, int n_in,
                              void* d_out, int out_size, void* d_ws, size_t ws_size,
                              hipStream_t stream)
{
    const float* q     = (const float*)d_in[0];
    const float* k     = (const float*)d_in[1];
    const float* v     = (const float*)d_in[2];
    const float* W     = (const float*)d_in[3];
    const float* Wb    = (const float*)d_in[4];
    const float* qg    = (const float*)d_in[5];
    const float* qb    = (const float*)d_in[6];
    const float* kg    = (const float*)d_in[7];
    const float* kbt   = (const float*)d_in[8];
    const float* vg    = (const float*)d_in[9];
    const float* vbt   = (const float*)d_in[10];
    const float* pw    = (const float*)d_in[11];
    const float* pg    = (const float*)d_in[13];
    const float* pbeta = (const float*)d_in[14];

    // workspace carve (~14 MB)
    char* p = (char*)d_ws;
    u64* qmv = (u64*)p;                     p += (size_t)TDIM * BDIM * HDIM * NDIM * 8; // 2MB
    u64* kbits = (u64*)p;                   p += (size_t)TDIM * BDIM * C * 16 * 8;      // 2MB
    u64* vbits = (u64*)p;                   p += (size_t)TDIM * BDIM * C * 16 * 8;      // 2MB
    u16* Ps = (u16*)p;                      p += (size_t)3 * 262144 * 2;                // 1.57MB
    unsigned char* spkT = (unsigned char*)p; p += (size_t)BCN;                          // 4.19MB
    _Float16* ktvT = (_Float16*)p;          p += (size_t)TDIM * BDIM * HDIM * 64 * 64 * 2; // 2.1MB
    float* mean3 = (float*)p;               p += 8192;   // 1536 used
    float* rstd3 = (float*)p;               p += 8192;

    // d_out scratch: Y3 (50.3MB of 67.1MB), dead before gemm_proj overwrites.
    float* Y3 = (float*)d_out;
    float* outF = (float*)d_out;

    gemm_in3_k<<<dim3(8, 4, 24), 256, 0, stream>>>(W, Wb, q, k, v, Y3);
    chan_stats2_k<<<3 * C, 256, 0, stream>>>(Y3, mean3, rstd3, BDIM);
    spikes_k<<<4096, 256, 0, stream>>>(Y3, mean3, rstd3, qg, qb, kg, kbt, vg, vbt,
                                       pw, qmv, kbits, vbits, Ps);
    ktvT_k<<<256, 256, 0, stream>>>(kbits, vbits, ktvT);
    att_mfma_k<<<dim3(64, 16), 256, 0, stream>>>(ktvT, qmv, spkT);
    gemm_proj_mfma<<<dim3(8, 4, 32), 256, 0, stream>>>(Ps, spkT, outF);
    chan_stats2_k<<<C, 256, 0, stream>>>(outF, mean3, rstd3, TDIM * BDIM);
    final_bn_lif_k<<<BCN / 256, 256, 0, stream>>>(outF, mean3, rstd3, pg, pbeta);
}

// Round 15
// 518.041 us; speedup vs baseline: 1.1640x; 1.1640x over previous
//
#include <hip/hip_runtime.h>

#define C    512
#define NDIM 1024
#define BDIM 8
#define TDIM 4
#define HDIM 8
#define CN   (C*NDIM)        // 524288
#define BCN  (BDIM*CN)       // 4194304

typedef unsigned short u16;
typedef unsigned int   u32;
typedef unsigned long long u64;
typedef __attribute__((ext_vector_type(8))) short bf8v;      // 8 bf16 (4 VGPR)
typedef __attribute__((ext_vector_type(8))) _Float16 h8v;    // 8 fp16 (4 VGPR)
typedef __attribute__((ext_vector_type(4))) float f4v;       // 4 fp32 acc
typedef __attribute__((ext_vector_type(2))) float f2v;       // packed fp32 pair

// round-to-nearest-even f32 -> bf16 (finite inputs only)
__device__ __forceinline__ u16 f2bf(float f) {
    u32 u = __float_as_uint(f);
    u32 r = u + 0x7FFFu + ((u >> 16) & 1u);
    return (u16)(r >> 16);
}
__device__ __forceinline__ float bf2f(u16 h) { return __uint_as_float((u32)h << 16); }

#if defined(__has_builtin)
#if __has_builtin(__builtin_amdgcn_global_load_lds)
#define HAS_GLL 1
#endif
#if __has_builtin(__builtin_elementwise_fma)
#define HAS_EFMA 1
#endif
#endif
#ifdef HAS_GLL
#define GLD(gp, lp) __builtin_amdgcn_global_load_lds( \
    (const __attribute__((address_space(1))) u32*)(gp), \
    (__attribute__((address_space(3))) u32*)(lp), 16, 0, 0)
#else
#define GLD(gp, lp) (*(uint4*)(lp) = *(const uint4*)(const void*)(gp))
#endif

__device__ __forceinline__ f2v pkfma(f2v a, f2v b, f2v c) {
#ifdef HAS_EFMA
    return __builtin_elementwise_fma(a, b, c);
#else
    f2v r; r.x = fmaf(a.x, b.x, c.x); r.y = fmaf(a.y, b.y, c.y); return r;
#endif
}

// ---------------------------------------------------------------------------
// Merged in_proj fp32 GEMM (R10/R13-PROVEN: ~161 µs, 60 VGPR — empirical
// minimum. Escape routes measured and closed: R7 dbuf 188 VGPR→287 µs,
// R11 asm-pkfma→194 µs, R14 B-direct 136 VGPR→274 µs.)
// grid (8 nblk, 4 mblk, 24 = br*8+b)
// ---------------------------------------------------------------------------
__global__ __launch_bounds__(256) void gemm_in3_k(
    const float* __restrict__ W, const float* __restrict__ bias,
    const float* __restrict__ Xq, const float* __restrict__ Xk,
    const float* __restrict__ Xv, float* __restrict__ Y3)
{
    __shared__ float As[16][132];   // [k][m], pad 132
    __shared__ float Bs[16][132];   // [k][n]
    const int tid = threadIdx.x;
    const int bz = blockIdx.z;               // br*8 + b
    const int br = bz >> 3, b = bz & 7;
    const int m0 = blockIdx.y * 128;
    const int n0 = blockIdx.x * 128;
    const float* Xb = (br == 0 ? Xq : (br == 1 ? Xk : Xv)) + (size_t)b * CN;
    const int rowOff = br * 512;

    const int ra = tid >> 2, ka = (tid & 3) * 4;
    const int kb = tid >> 5, nb = (tid & 31) * 4;
    const int tx = tid & 15, ty = tid >> 4;

    const float* pA0 = &W[(size_t)(rowOff + m0 + ra) * 512 + ka];
    const float* pA1 = &W[(size_t)(rowOff + m0 + 64 + ra) * 512 + ka];
    const float* pB0 = &Xb[(size_t)kb * NDIM + n0 + nb];
    const float* pB1 = &Xb[(size_t)(kb + 8) * NDIM + n0 + nb];

    f2v acc[2][2][4][2];   // [mq][nq][i][jp]
    #pragma unroll
    for (int mq = 0; mq < 2; mq++)
        #pragma unroll
        for (int nq = 0; nq < 2; nq++)
            #pragma unroll
            for (int i = 0; i < 4; i++)
                #pragma unroll
                for (int jp = 0; jp < 2; jp++) acc[mq][nq][i][jp] = (f2v){0.f, 0.f};

    float4 a0 = *(const float4*)pA0;
    float4 a1 = *(const float4*)pA1;
    float4 b0 = *(const float4*)pB0;
    float4 b1 = *(const float4*)pB1;

    for (int k0 = 0; k0 < 512; k0 += 16) {
        __syncthreads();
        As[ka + 0][ra] = a0.x; As[ka + 1][ra] = a0.y;
        As[ka + 2][ra] = a0.z; As[ka + 3][ra] = a0.w;
        As[ka + 0][64 + ra] = a1.x; As[ka + 1][64 + ra] = a1.y;
        As[ka + 2][64 + ra] = a1.z; As[ka + 3][64 + ra] = a1.w;
        *(float4*)&Bs[kb][nb]     = b0;
        *(float4*)&Bs[kb + 8][nb] = b1;
        __syncthreads();
        if (k0 < 496) {
            a0 = *(const float4*)(pA0 + k0 + 16);
            a1 = *(const float4*)(pA1 + k0 + 16);
            b0 = *(const float4*)(pB0 + (size_t)(k0 + 16) * NDIM);
            b1 = *(const float4*)(pB1 + (size_t)(k0 + 16) * NDIM);
        }
        #pragma unroll
        for (int k = 0; k < 16; k++) {
            float av[2][4];
            f2v bv[2][2];
            *(float4*)av[0] = *(const float4*)&As[k][ty * 4];
            *(float4*)av[1] = *(const float4*)&As[k][64 + ty * 4];
            float4 bq0 = *(const float4*)&Bs[k][tx * 4];
            float4 bq1 = *(const float4*)&Bs[k][64 + tx * 4];
            bv[0][0] = (f2v){bq0.x, bq0.y}; bv[0][1] = (f2v){bq0.z, bq0.w};
            bv[1][0] = (f2v){bq1.x, bq1.y}; bv[1][1] = (f2v){bq1.z, bq1.w};
            #pragma unroll
            for (int mq = 0; mq < 2; mq++)
                #pragma unroll
                for (int i = 0; i < 4; i++) {
                    const f2v a2 = (f2v){av[mq][i], av[mq][i]};
                    #pragma unroll
                    for (int nq = 0; nq < 2; nq++)
                        #pragma unroll
                        for (int jp = 0; jp < 2; jp++)
                            acc[mq][nq][i][jp] = pkfma(a2, bv[nq][jp], acc[mq][nq][i][jp]);
                }
        }
    }
    #pragma unroll
    for (int mq = 0; mq < 2; mq++)
        #pragma unroll
        for (int i = 0; i < 4; i++) {
            const int mrow = mq * 64 + ty * 4 + i;
            float bsv = bias[rowOff + m0 + mrow];
            float* yr = Y3 + (size_t)bz * CN + (size_t)(m0 + mrow) * NDIM + n0;
            #pragma unroll
            for (int nq = 0; nq < 2; nq++) {
                float4 o4 = make_float4(acc[mq][nq][i][0].x + bsv, acc[mq][nq][i][0].y + bsv,
                                        acc[mq][nq][i][1].x + bsv, acc[mq][nq][i][1].y + bsv);
                *(float4*)&yr[nq * 64 + tx * 4] = o4;
            }
        }
}

// ---------------------------------------------------------------------------
// Fused two-pass per-channel stats (R7/R8-proven, bit-exact vs R6 pair)
// ---------------------------------------------------------------------------
__global__ __launch_bounds__(256) void chan_stats2_k(
    const float* __restrict__ X3, float* __restrict__ mean3,
    float* __restrict__ rstd3, int outer)
{
    __shared__ float red[256];
    __shared__ float m_sh;
    const int gb = blockIdx.x;
    const int o = gb & (C - 1);
    const float* X = X3 + (size_t)(gb >> 9) * BCN;
    const int tid = threadIdx.x;
    const int total = outer * NDIM;
    float s = 0.f;
    for (int i = tid; i < total; i += 256) {
        int ou = i >> 10, n = i & 1023;
        s += X[(size_t)(ou * C + o) * NDIM + n];
    }
    red[tid] = s; __syncthreads();
    for (int off = 128; off > 0; off >>= 1) {
        if (tid < off) red[tid] += red[tid + off];
        __syncthreads();
    }
    if (tid == 0) { float m = red[0] / (float)total; mean3[gb] = m; m_sh = m; }
    __syncthreads();
    const float m = m_sh;
    float s2 = 0.f;
    for (int i = tid; i < total; i += 256) {
        int ou = i >> 10, n = i & 1023;
        float d = X[(size_t)(ou * C + o) * NDIM + n] - m;
        s2 += d * d;
    }
    red[tid] = s2; __syncthreads();
    for (int off = 128; off > 0; off >>= 1) {
        if (tid < off) red[tid] += red[tid + off];
        __syncthreads();
    }
    if (tid == 0) rstd3[gb] = 1.f / sqrtf(red[0] / (float)total + 1e-5f);
}

// ---------------------------------------------------------------------------
// One dispatch: Q BN+LIF+qpack, K/V BN+LIF+bitpack, PW split (R7/R8-proven)
// ---------------------------------------------------------------------------
__global__ __launch_bounds__(256) void spikes_k(
    const float* __restrict__ Y3, const float* __restrict__ mean3,
    const float* __restrict__ rstd3,
    const float* __restrict__ qg, const float* __restrict__ qb,
    const float* __restrict__ kg, const float* __restrict__ kbt,
    const float* __restrict__ vg, const float* __restrict__ vbt,
    const float* __restrict__ PW,
    u64* __restrict__ qm, u64* __restrict__ kbits, u64* __restrict__ vbits,
    u16* __restrict__ Ps)
{
    __shared__ unsigned char tile[64][68];
    const int tid = threadIdx.x;
    const int bid = blockIdx.x;
    if (bid < 1024) {
        const int b = bid >> 7, h = (bid >> 4) & 7, nt = bid & 15;
        const int c_l = tid >> 2, sg = (tid & 3) * 16;
        const int o = h * 64 + c_l;
        const float m = mean3[o], rs = rstd3[o], g = qg[o], bt = qb[o];
        const float* Yr = Y3 + ((size_t)b * C + o) * NDIM + nt * 64 + sg;
        #pragma unroll
        for (int j = 0; j < 4; j++) {
            float4 y4 = *(const float4*)&Yr[j * 4];
            float ys[4] = {y4.x, y4.y, y4.z, y4.w};
            #pragma unroll
            for (int e = 0; e < 4; e++) {
                float x = g * (ys[e] - m);
                x = x * rs + bt;
                float v = 0.f; unsigned bits = 0;
                #pragma unroll
                for (int t = 0; t < 4; t++) {
                    v += (x - v) * 0.5f;
                    if (v - 1.0f >= 0.f) { bits |= (1u << t); v = 0.f; }
                }
                tile[c_l][sg + j * 4 + e] = (unsigned char)bits;
            }
        }
        __syncthreads();
        const int lane = tid & 63, wv = tid >> 6;
        #pragma unroll
        for (int i = 0; i < 16; i++) {
            const int nl = wv * 16 + i;
            unsigned s = tile[lane][nl];
            #pragma unroll
            for (int t = 0; t < 4; t++) {
                u64 mk = __ballot((s >> t) & 1);
                if (lane == t)
                    qm[(size_t)((t * BDIM + b) * HDIM + h) * NDIM + nt * 64 + nl] = mk;
            }
        }
    } else if (bid < 3072) {
        const int r = bid - 1024;
        const int br = r >> 10;                       // 0:K 1:V
        const int rr = r & 1023;
        const int b = rr >> 7, ct = (rr >> 4) & 7, nt = rr & 15;
        const float* Yb = Y3 + (size_t)(br + 1) * BCN + (size_t)b * CN;
        const float* mean = mean3 + (br + 1) * C;
        const float* rstd = rstd3 + (br + 1) * C;
        const float* gam = br == 0 ? kg : vg;
        const float* bet = br == 0 ? kbt : vbt;
        u64* bits = br == 0 ? kbits : vbits;
        const int lane = tid & 63, wv = tid >> 6;
        #pragma unroll
        for (int i = 0; i < 16; i++) {
            const int o = ct * 64 + wv * 16 + i;
            const float m = mean[o], rs = rstd[o], g = gam[o], bt = bet[o];
            float y = Yb[(size_t)o * NDIM + nt * 64 + lane];
            float x = g * (y - m);
            x = x * rs + bt;
            float v = 0.f; unsigned sb = 0;
            #pragma unroll
            for (int t = 0; t < 4; t++) {
                v += (x - v) * 0.5f;
                if (v - 1.0f >= 0.f) { sb |= (1u << t); v = 0.f; }
            }
            #pragma unroll
            for (int t = 0; t < 4; t++) {
                u64 mk = __ballot((sb >> t) & 1);
                if (lane == t)
                    bits[((size_t)(t * BDIM + b) * C + o) * 16 + nt] = mk;
            }
        }
    } else {
        const int idx = (bid - 3072) * 256 + tid;     // 262144 PW elements
        float x = PW[idx];
        u16 h1 = f2bf(x); float r1 = x - bf2f(h1);
        u16 h2 = f2bf(r1); float r2 = r1 - bf2f(h2);
        u16 h3 = f2bf(r2);
        Ps[idx] = h1; Ps[idx + 262144] = h2; Ps[idx + 2 * 262144] = h3;
    }
}

// ---------------------------------------------------------------------------
// ktvT[t,b,h,e,dd] = popcount(K & V), transposed, fp16-exact (R10-proven)
// ---------------------------------------------------------------------------
__global__ __launch_bounds__(256) void ktvT_k(
    const u64* __restrict__ kb, const u64* __restrict__ vb,
    _Float16* __restrict__ ktvT)
{
    __shared__ u64 kst[64][17];
    __shared__ u64 vst[64][17];
    const int tid = threadIdx.x;
    const int g = blockIdx.x;
    const int h = g & 7, b = (g >> 3) & 7, t = g >> 6;
    const size_t base = ((size_t)(t * BDIM + b) * C + h * 64) * 16;
    {
        int r = tid >> 2, w0 = (tid & 3) * 4;
        #pragma unroll
        for (int j = 0; j < 4; j++) {
            kst[r][w0 + j] = kb[base + r * 16 + w0 + j];
            vst[r][w0 + j] = vb[base + r * 16 + w0 + j];
        }
    }
    __syncthreads();
    const int e = tid >> 2, dd0 = (tid & 3) * 16;
    u64 vr[16];
    #pragma unroll
    for (int w = 0; w < 16; w++) vr[w] = vst[e][w];
    #pragma unroll
    for (int i = 0; i < 16; i++) {
        int dd = dd0 + i;
        int s = 0;
        #pragma unroll
        for (int w = 0; w < 16; w++) s += __popcll(kst[dd][w] & vr[w]);
        ktvT[(size_t)(g * 64 + e) * 64 + dd] = (_Float16)s;
    }
}

// ---------------------------------------------------------------------------
// att via fp16 MFMA (exact) + attn LIF (vth=0.5)  (R10-proven)
// ---------------------------------------------------------------------------
__global__ __launch_bounds__(256) void att_mfma_k(
    const _Float16* __restrict__ ktvT, const u64* __restrict__ qm,
    unsigned char* __restrict__ spkT)
{
    const int tid = threadIdx.x;
    const int w = tid >> 6, lane = tid & 63;
    const int ln = lane & 15, q = lane >> 4;
    const int bh = blockIdx.x; const int h = bh & 7, b = bh >> 3;
    const int n0 = blockIdx.y * 64 + w * 16;

    float v[4][4];
    u32 bits[4][4];
    #pragma unroll
    for (int et = 0; et < 4; et++)
        #pragma unroll
        for (int r = 0; r < 4; r++) { v[et][r] = 0.f; bits[et][r] = 0u; }

    #pragma unroll
    for (int t = 0; t < 4; t++) {
        const size_t gq = (size_t)(t * BDIM + b) * HDIM + h;
        const u64 qw = qm[gq * NDIM + n0 + ln];
        union { u16 s[8]; h8v v8; } a0u, a1u;
        #pragma unroll
        for (int j = 0; j < 8; j++) {
            a0u.s[j] = (u16)(((qw >> (q * 8 + j)) & 1ull) ? 0x3C00u : 0u);
            a1u.s[j] = (u16)(((qw >> (32 + q * 8 + j)) & 1ull) ? 0x3C00u : 0u);
        }
        const _Float16* kbp = ktvT + gq * 4096;
        f4v acc[4];
        #pragma unroll
        for (int et = 0; et < 4; et++) acc[et] = (f4v){0.f, 0.f, 0.f, 0.f};
        #pragma unroll
        for (int et = 0; et < 4; et++) {
            h8v b0 = *(const h8v*)(kbp + (et * 16 + ln) * 64 + q * 8);
            h8v b1 = *(const h8v*)(kbp + (et * 16 + ln) * 64 + 32 + q * 8);
            acc[et] = __builtin_amdgcn_mfma_f32_16x16x32_f16(a0u.v8, b0, acc[et], 0, 0, 0);
            acc[et] = __builtin_amdgcn_mfma_f32_16x16x32_f16(a1u.v8, b1, acc[et], 0, 0, 0);
        }
        #pragma unroll
        for (int et = 0; et < 4; et++)
            #pragma unroll
            for (int r = 0; r < 4; r++) {
                float x = acc[et][r] * 0.125f;     // exact dyadic
                float vv = v[et][r];
                vv += (x - vv) * 0.5f;
                if (vv - 0.5f >= 0.f) { bits[et][r] |= (1u << t); vv = 0.f; }
                v[et][r] = vv;
            }
    }
    #pragma unroll
    for (int et = 0; et < 4; et++)
        #pragma unroll
        for (int r = 0; r < 4; r++)
            spkT[((size_t)b * 1024 + n0 + q * 4 + r) * 512 + h * 64 + et * 16 + ln] =
                (unsigned char)bits[et][r];
}

// ---------------------------------------------------------------------------
// proj MFMA GEMM over spikes (R3-PROVEN version — 81 µs plateau)
// ---------------------------------------------------------------------------
__global__ __launch_bounds__(256, 2) void gemm_proj_mfma(
    const u16* __restrict__ Ps, const unsigned char* __restrict__ spkT,
    float* __restrict__ Z)
{
    __shared__ __align__(16) u16 Ab[2][12288];   // 3 splits x 4096
    __shared__ __align__(16) u16 Bb[2][4096];
    const int tid = threadIdx.x;
    const int zb = blockIdx.z, t = zb >> 3, bb = zb & 7;
    const int m0 = blockIdx.y * 128, n0 = blockIdx.x * 128;

    u32 aoff[2][3];
    int lofs[2];
    #pragma unroll
    for (int r = 0; r < 2; r++) {
        const int cid = tid + (r << 8);
        const int mm = cid & 15, kg = (cid >> 4) & 3, mt = cid >> 6;
        lofs[r] = cid * 8;
        #pragma unroll
        for (int s = 0; s < 3; s++)
            aoff[r][s] = (u32)s * 262144u + (u32)(m0 + mt * 16 + mm) * 512u + kg * 8;
    }
    auto stageA = [&](int ki2, int p2) {
        const u32 kk = (u32)ki2 << 5;
        #pragma unroll
        for (int r = 0; r < 2; r++)
            #pragma unroll
            for (int s = 0; s < 3; s++)
                GLD(Ps + aoff[r][s] + kk, &Ab[p2][s * 4096 + lofs[r]]);
    };
    const int nn = tid & 15, ntl = (tid >> 4) & 7, seg = tid >> 7;
    const u32 srcB = ((u32)bb * 1024u + (u32)(n0 + ntl * 16 + nn)) * 512u + seg * 16;
    const int ldsB0 = (ntl * 64 + seg * 32 + nn) * 8;
    auto convB = [&](uint4 braw, int p2) {
        u32 bs[4] = {braw.x, braw.y, braw.z, braw.w};
        u32 wreg[8];
        #pragma unroll
        for (int qq = 0; qq < 4; qq++) {
            u32 vv = bs[qq] >> t;
            wreg[qq * 2 + 0] = ((vv & 1u) ? 0x3F80u : 0u) | ((vv & 0x100u) ? 0x3F800000u : 0u);
            wreg[qq * 2 + 1] = (((vv >> 16) & 1u) ? 0x3F80u : 0u) | ((vv & 0x1000000u) ? 0x3F800000u : 0u);
        }
        *(uint4*)&Bb[p2][ldsB0]       = make_uint4(wreg[0], wreg[1], wreg[2], wreg[3]);
        *(uint4*)&Bb[p2][ldsB0 + 128] = make_uint4(wreg[4], wreg[5], wreg[6], wreg[7]);
    };

    const int lane = tid & 63, wv = tid >> 6;
    const int wm = wv >> 1, wn = wv & 1;
    const int q = lane >> 4, ln = lane & 15;
    int afo[4], bfo[4];
    #pragma unroll
    for (int i = 0; i < 4; i++) {
        afo[i] = ((wm * 4 + i) * 64 + q * 16 + ln) * 8;
        bfo[i] = ((wn * 4 + i) * 64 + q * 16 + ln) * 8;
    }

    f4v acc[4][4];
    #pragma unroll
    for (int i = 0; i < 4; i++)
        #pragma unroll
        for (int j = 0; j < 4; j++) acc[i][j] = (f4v){0.f, 0.f, 0.f, 0.f};

    stageA(0, 0);
    convB(*(const uint4*)&spkT[srcB], 0);
    uint4 braw;
    for (int ki = 0; ki < 16; ki++) {
        const int p = ki & 1;
        __syncthreads();
        if (ki < 15) {
            stageA(ki + 1, p ^ 1);
            braw = *(const uint4*)&spkT[srcB + ((u32)(ki + 1) << 5)];
        }
        bf8v bf[4];
        #pragma unroll
        for (int j = 0; j < 4; j++) bf[j] = *(const bf8v*)&Bb[p][bfo[j]];
        #pragma unroll
        for (int sa = 0; sa < 3; sa++) {
            bf8v af[4];
            #pragma unroll
            for (int i = 0; i < 4; i++) af[i] = *(const bf8v*)&Ab[p][sa * 4096 + afo[i]];
            #pragma unroll
            for (int i = 0; i < 4; i++)
                #pragma unroll
                for (int j = 0; j < 4; j++)
                    acc[i][j] = __builtin_amdgcn_mfma_f32_16x16x32_bf16(af[i], bf[j], acc[i][j], 0, 0, 0);
        }
        if (ki < 15) convB(braw, p ^ 1);
    }
    float* Zb = Z + (size_t)zb * CN;
    #pragma unroll
    for (int i = 0; i < 4; i++) {
        const int row = m0 + (wm * 4 + i) * 16 + q * 4;
        #pragma unroll
        for (int g = 0; g < 4; g++) {
            float* zr = Zb + (size_t)(row + g) * 1024 + n0 + ln;
            #pragma unroll
            for (int j = 0; j < 4; j++)
                zr[(wn * 4 + j) * 16] = acc[i][j][g];
        }
    }
}

// ---------------------------------------------------------------------------
// Final BN + LIF (vth=1, time-varying) in place over d_out.  (R3-proven)
// ---------------------------------------------------------------------------
__global__ __launch_bounds__(256) void final_bn_lif_k(
    float* __restrict__ Z, const float* __restrict__ mean,
    const float* __restrict__ rstd, const float* __restrict__ gamma,
    const float* __restrict__ beta)
{
    const int idx = blockIdx.x * 256 + threadIdx.x;
    const int o = (idx >> 10) & (C - 1);
    const float m = mean[o], rs = rstd[o], g = gamma[o], bt = beta[o];
    float v = 0.f;
    float outs[4];
    #pragma unroll
    for (int t = 0; t < 4; t++) {
        float z = Z[(size_t)t * BCN + idx];
        float x = g * (z - m);
        x = x * rs + bt;
        v += (x - v) * 0.5f;
        float s = (v - 1.0f >= 0.f) ? 1.f : 0.f;
        v *= (1.f - s);
        outs[t] = s;
    }
    #pragma unroll
    for (int t = 0; t < 4; t++) Z[(size_t)t * BCN + idx] = outs[t];
}

// ---------------------------------------------------------------------------
extern "C" void kernel_launch(void* const* d_in, const int* in_sizes, int n_in,
                              void* d_out, int out_size, void* d_ws, size_t ws_size,
                              hipStream_t stream)
{
    const float* q     = (const float*)d_in[0];
    const float* k     = (const float*)d_in[1];
    const float* v     = (const float*)d_in[2];
    const float* W     = (const float*)d_in[3];
    const float* Wb    = (const float*)d_in[4];
    const float* qg    = (const float*)d_in[5];
    const float* qb    = (const float*)d_in[6];
    const float* kg    = (const float*)d_in[7];
    const float* kbt   = (const float*)d_in[8];
    const float* vg    = (const float*)d_in[9];
    const float* vbt   = (const float*)d_in[10];
    const float* pw    = (const float*)d_in[11];
    const float* pg    = (const float*)d_in[13];
    const float* pbeta = (const float*)d_in[14];

    // workspace carve (~14 MB)
    char* p = (char*)d_ws;
    u64* qmv = (u64*)p;                     p += (size_t)TDIM * BDIM * HDIM * NDIM * 8; // 2MB
    u64* kbits = (u64*)p;                   p += (size_t)TDIM * BDIM * C * 16 * 8;      // 2MB
    u64* vbits = (u64*)p;                   p += (size_t)TDIM * BDIM * C * 16 * 8;      // 2MB
    u16* Ps = (u16*)p;                      p += (size_t)3 * 262144 * 2;                // 1.57MB
    unsigned char* spkT = (unsigned char*)p; p += (size_t)BCN;                          // 4.19MB
    _Float16* ktvT = (_Float16*)p;          p += (size_t)TDIM * BDIM * HDIM * 64 * 64 * 2; // 2.1MB
    float* mean3 = (float*)p;               p += 8192;   // 1536 used
    float* rstd3 = (float*)p;               p += 8192;

    // d_out scratch: Y3 (50.3MB of 67.1MB), dead before gemm_proj overwrites.
    float* Y3 = (float*)d_out;
    float* outF = (float*)d_out;

    gemm_in3_k<<<dim3(8, 4, 24), 256, 0, stream>>>(W, Wb, q, k, v, Y3);
    chan_stats2_k<<<3 * C, 256, 0, stream>>>(Y3, mean3, rstd3, BDIM);
    spikes_k<<<4096, 256, 0, stream>>>(Y3, mean3, rstd3, qg, qb, kg, kbt, vg, vbt,
                                       pw, qmv, kbits, vbits, Ps);
    ktvT_k<<<256, 256, 0, stream>>>(kbits, vbits, ktvT);
    att_mfma_k<<<dim3(64, 16), 256, 0, stream>>>(ktvT, qmv, spkT);
    gemm_proj_mfma<<<dim3(8, 4, 32), 256, 0, stream>>>(Ps, spkT, outF);
    chan_stats2_k<<<C, 256, 0, stream>>>(outF, mean3, rstd3, TDIM * BDIM);
    final_bn_lif_k<<<BCN / 256, 256, 0, stream>>>(outF, mean3, rstd3, pg, pbeta);
}